// Round 10
// baseline (2628.402 us; speedup 1.0000x reference)
//
#include <hip/hip_runtime.h>
#include <cmath>
#include <cstdint>

#define NWG 256
#define NT  256

// dims: B=16, T=64, L=64, D=512, A=256, 4D=2048
// ws float offsets
#define WS_FLAGS 0         // u32 flags[256][16]: w0 = gsync, w2 = att-partials (16 KB)
#define WS_PSC   4096      // 128 groups x 128 floats: attention score partials (bypass)
#define WS_HC    20480     // 16*512  (h_ctx, rewritten per step; bypass-only)
#define WS_CT    28672     // 16*64*256 ctx_trans (write-once prologue, cached reads)
#define WS_CACHE 290816    // 16*64*256 hist proj rows (same-WG write+read per quarter, cached)
#define WS_HIST  552960    // 16*64*512 h history rows (write-once; bypass write / cached reads)
#define WS_HHP   1077248   // 512*256 u32: packed (bf16 hthW1 | bf16 hhW<<16) (write-once)
#define WS_AHB   1208320   // 512*128 u32: bf16 ahW1 col-pairs (write-once)
// end: 1273856 floats = 4.86 MB

// out float offsets (hs | cs | ctxs)
#define OUT_HS  0
#define OUT_CS  524288
#define OUT_CTX 1048576

// lds float offsets
#define LDS_WT   0        // 4 quarters x 5136 (2560 K rows * 2 cols interleaved + pad)
#define LDS_ZS   20544    // z-stage [16 b][516]
#define LDS_SCR  28800    // scratch 2048 (gemm reduce / einsum+proj partials / prologue)
#define LDS_GLD  30848    // g lds 16*8
#define LDS_ATT  30976    // aw 256 | av2 256 | abv 256 | araw 96 | asmx 64
#define LDS_FLOATS 31904  // *4 = 127,616 B < 160 KB

typedef float vf4 __attribute__((ext_vector_type(4)));
typedef float vf2 __attribute__((ext_vector_type(2)));

struct CAParams {
  const float* X; const float* ctx; const int* parent; const int* cmask; const float* mask;
  const float* Wx; const float* bx; const float* U; const float* C; const float* P; const float* H;
  const float* acW1; const float* ab1; const float* ahW1; const float* aW2; const float* ab2;
  const float* hhW; const float* hhb; const float* hthW1; const float* hW2; const float* hb2;
  float* out; float* ws;
};

__device__ __forceinline__ float tanh_f(float x) {
  x = fminf(15.f, fmaxf(-15.f, x));
  float e = __expf(2.f * x);
  return (e - 1.f) / (e + 1.f);
}
__device__ __forceinline__ float sigm_f(float x) { return 1.f / (1.f + __expf(-x)); }
__device__ __forceinline__ float wsum(float v) {
  #pragma unroll
  for (int m = 32; m; m >>= 1) v += __shfl_xor(v, m, 64);
  return v;
}
__device__ __forceinline__ float wmax(float v) {
  #pragma unroll
  for (int m = 32; m; m >>= 1) v = fmaxf(v, __shfl_xor(v, m, 64));
  return v;
}
__device__ __forceinline__ float hsum32(float v) {  // reduce within 32-lane half
  #pragma unroll
  for (int m = 16; m; m >>= 1) v += __shfl_xor(v, m, 64);
  return v;
}
// bf16 round-to-nearest-even
__device__ __forceinline__ uint32_t f2bf(float f) {
  uint32_t u = __float_as_uint(f);
  return (u + 0x7FFFu + ((u >> 16) & 1u)) >> 16;
}

// ---- MALL-coherent bypass ops (sc0 sc1), non-atomic so they pipeline ----
__device__ __forceinline__ void bst(float* a, float v) {
  asm volatile("global_store_dword %0, %1, off sc0 sc1" :: "v"(a), "v"(v) : "memory");
}
__device__ __forceinline__ void bstu(uint32_t* a, uint32_t v) {
  asm volatile("global_store_dword %0, %1, off sc0 sc1" :: "v"(a), "v"(v) : "memory");
}
__device__ __forceinline__ void bst4(float* a, vf4 v) {
  asm volatile("global_store_dwordx4 %0, %1, off sc0 sc1" :: "v"(a), "v"(v) : "memory");
}
// 4 scalar bypass loads in flight, one drain
__device__ __forceinline__ vf4 bld4s(const float* a0, const float* a1, const float* a2, const float* a3) {
  float r0, r1, r2, r3;
  asm volatile(
    "global_load_dword %0, %4, off sc0 sc1\n"
    "global_load_dword %1, %5, off sc0 sc1\n"
    "global_load_dword %2, %6, off sc0 sc1\n"
    "global_load_dword %3, %7, off sc0 sc1\n"
    "s_waitcnt vmcnt(0)"
    : "=&v"(r0),"=&v"(r1),"=&v"(r2),"=&v"(r3)
    : "v"(a0),"v"(a1),"v"(a2),"v"(a3) : "memory");
  vf4 v; v.x = r0; v.y = r1; v.z = r2; v.w = r3; return v;
}
// issue-only 8-deep bypass loads; pair with bwait8 (data-dep via +v prevents hoisting)
__device__ __forceinline__ void bld8_issue(vf4* r, const float* q0, const float* q1, const float* q2, const float* q3,
                                           const float* q4, const float* q5, const float* q6, const float* q7) {
  asm volatile(
    "global_load_dwordx4 %0, %8, off sc0 sc1\n"
    "global_load_dwordx4 %1, %9, off sc0 sc1\n"
    "global_load_dwordx4 %2, %10, off sc0 sc1\n"
    "global_load_dwordx4 %3, %11, off sc0 sc1\n"
    "global_load_dwordx4 %4, %12, off sc0 sc1\n"
    "global_load_dwordx4 %5, %13, off sc0 sc1\n"
    "global_load_dwordx4 %6, %14, off sc0 sc1\n"
    "global_load_dwordx4 %7, %15, off sc0 sc1"
    : "=&v"(r[0]),"=&v"(r[1]),"=&v"(r[2]),"=&v"(r[3]),"=&v"(r[4]),"=&v"(r[5]),"=&v"(r[6]),"=&v"(r[7])
    : "v"(q0),"v"(q1),"v"(q2),"v"(q3),"v"(q4),"v"(q5),"v"(q6),"v"(q7)
    : "memory");
}
__device__ __forceinline__ void bwait8(vf4* r) {
  asm volatile("s_waitcnt vmcnt(0)"
    : "+v"(r[0]),"+v"(r[1]),"+v"(r[2]),"+v"(r[3]),"+v"(r[4]),"+v"(r[5]),"+v"(r[6]),"+v"(r[7])
    :: "memory");
}

__global__ void __launch_bounds__(NT, 1) condatt_kernel(CAParams p) {
  extern __shared__ float lds[];
  float* wt   = lds + LDS_WT;
  float* zs   = lds + LDS_ZS;
  float* scr  = lds + LDS_SCR;
  float* gld  = lds + LDS_GLD;
  float* aw   = lds + LDS_ATT;
  float* av2  = lds + LDS_ATT + 256;
  float* abv  = lds + LDS_ATT + 512;
  float* araw = lds + LDS_ATT + 768;   // 96 (idx 64 = z-score)
  float* asmx = lds + LDS_ATT + 864;   // 64

  const int tid = threadIdx.x;
  const int wg  = blockIdx.x;
  float* wsp = p.ws;
  unsigned* flags = (unsigned*)wsp;
  unsigned nbar = 0;

  // XCD-contiguous gate-column assignment (wg%8 = XCD)
  const int base = 2 * ((wg & 7) * 32 + (wg >> 3));  // gate col pair {base, base+1}

  // attention group assignment: 128 att WGs, 4 per (type, b)
  const bool isAtt  = wg < 128;
  const bool isHist = wg >= 64;
  const int  ab   = (wg & 63) >> 2;       // batch row
  const int  Q    = wg & 3;               // a-quarter
  const int  grp0 = (wg & 64) + ab * 4;   // base WG id of the 4-WG group

  // discard stale L1/L2 lines from previous dispatch/poison blit
  __threadfence_system();

  const int kh = tid >> 4, sub = tid & 15, bg = sub >> 2, cp = sub & 3;
  float acc[4][2] = {{0.f,0.f},{0.f,0.f},{0.f,0.f},{0.f,0.f}};
  float hprev = 0.f, cprev = 0.f;  // threads 0..31: per-(b,d) recurrent state

  auto gsync = [&]() {
    asm volatile("s_waitcnt vmcnt(0)" ::: "memory");
    __syncthreads();
    ++nbar;
    if (tid == 0)
      __hip_atomic_store(&flags[wg * 16], nbar, __ATOMIC_RELAXED, __HIP_MEMORY_SCOPE_SYSTEM);
    while (__hip_atomic_load(&flags[tid * 16], __ATOMIC_RELAXED, __HIP_MEMORY_SCOPE_SYSTEM) < nbar)
      __builtin_amdgcn_s_sleep(1);
    __syncthreads();
  };

  // ---------------- prologue ----------------
  {
    // ctx_trans = context @ att_ctx_W1 + att_b1 : 4 (b,l)-rows per wg
    for (int j = 0; j < 4; ++j) {
      int rid = wg * 4 + j;  // rid = b*64 + l
      __syncthreads();
      for (int i = tid; i < 512; i += NT) scr[i] = p.ctx[rid * 512 + i];
      __syncthreads();
      float a0 = 0.f, a1 = 0.f, a2 = 0.f, a3 = 0.f;
      for (int c = 0; c < 512; c += 4) {
        a0 += scr[c+0] * p.acW1[(c+0) * 256 + tid];
        a1 += scr[c+1] * p.acW1[(c+1) * 256 + tid];
        a2 += scr[c+2] * p.acW1[(c+2) * 256 + tid];
        a3 += scr[c+3] * p.acW1[(c+3) * 256 + tid];
      }
      bst(wsp + WS_CT + rid * 256 + tid, p.ab1[tid] + ((a0 + a1) + (a2 + a3)));
    }
    __syncthreads();
    // persistent gate-GEMM weights
    const float* mats[5] = {p.Wx, p.U, p.P, p.C, p.H};
    for (int q = 0; q < 4; ++q) {
      for (int r = tid; r < 2560; r += NT) {
        int m = r >> 9, rr = r & 511;
        vf2 v = *(const vf2*)(mats[m] + rr * 2048 + base + 512 * q);
        *(vf2*)(wt + q * 5136 + r * 2) = v;
      }
    }
    // bf16-packed projection weights (distributed build, bypass-published)
    {
      uint32_t* hpd = (uint32_t*)(wsp + WS_HHP);
      for (int i = wg * NT + tid; i < 131072; i += NWG * NT) {
        uint32_t lo = f2bf(p.hthW1[i]);
        uint32_t hi = f2bf(p.hhW[i]);
        bstu(hpd + i, lo | (hi << 16));
      }
      uint32_t* ahd = (uint32_t*)(wsp + WS_AHB);
      for (int j = wg * NT + tid; j < 65536; j += NWG * NT) {
        uint32_t lo = f2bf(p.ahW1[j * 2]);
        uint32_t hi = f2bf(p.ahW1[j * 2 + 1]);
        bstu(ahd + j, lo | (hi << 16));
      }
    }
    // att WGs: persistent score vectors
    if (isAtt) {
      if (!isHist) { av2[tid] = p.aW2[tid]; }
      else         { av2[tid] = p.hW2[tid]; abv[tid] = p.hhb[tid]; }
    }
    // stage X(0) and do the x-part GEMM before the loop
    #pragma unroll
    for (int j = 0; j < 8; ++j) {
      int i4 = tid + j * NT, b = i4 >> 7, k0 = (i4 << 2) & 511;
      vf4 v = *(const vf4*)(p.X + (b * 64 + 0) * 512 + k0);
      *(vf4*)(zs + b * 516 + k0) = v;
    }
    __syncthreads();
  }

  auto gemm = [&](int comp) {
    const float* wp = wt + cp * 5136 + comp * 1024;
    const float* zb = zs + (bg * 4) * 516;
    #pragma unroll 4
    for (int j = 0; j < 32; ++j) {
      int k = kh + (j << 4);
      vf2 w = *(const vf2*)(wp + k * 2);
      float z0 = zb[k], z1 = zb[516 + k], z2 = zb[1032 + k], z3 = zb[1548 + k];
      acc[0][0] += z0 * w.x; acc[0][1] += z0 * w.y;
      acc[1][0] += z1 * w.x; acc[1][1] += z1 * w.y;
      acc[2][0] += z2 * w.x; acc[2][1] += z2 * w.y;
      acc[3][0] += z3 * w.x; acc[3][1] += z3 * w.y;
    }
  };

  const float ab2f = *p.ab2;
  const float hb2f = *p.hb2;

  gemm(0);   // x-part for t=0
  gsync();   // publish CT + packed weights before t=0 attention

  for (int t = 0; t < 64; ++t) {
    // ================= Phase A =================
    // stage h (= HIST row t-1) into zs (all WGs)
    __syncthreads();
    if (t == 0) {
      vf4 z = {0.f, 0.f, 0.f, 0.f};
      #pragma unroll
      for (int j = 0; j < 8; ++j) {
        int i4 = tid + j * NT, b = i4 >> 7, k0 = (i4 << 2) & 511;
        *(vf4*)(zs + b * 516 + k0) = z;
      }
    } else {
      #pragma unroll
      for (int j = 0; j < 8; ++j) {
        int i4 = tid + j * NT, b = i4 >> 7, k0 = (i4 << 2) & 511;
        vf4 v = *(const vf4*)(wsp + WS_HIST + (b * 64 + (t - 1)) * 512 + k0);
        *(vf4*)(zs + b * 516 + k0) = v;
      }
    }
    __syncthreads();

    // att WGs: quarter-proj + partial scores, publish, then gate gemms hide handoff
    if (isAtt) {
      const float* hb = zs + ab * 516;   // this b's h vector (LDS broadcast reads)
      if (!isHist) {
        // ctx quarter: a in [Q*64, Q*64+64) -> 64 KB bf16 stream
        const uint32_t* ahd = (const uint32_t*)(wsp + WS_AHB);
        int pl = tid & 31, kq = tid >> 5;
        int pcolI = Q * 32 + pl;
        float s0 = 0.f, s1 = 0.f;
        #pragma unroll 16
        for (int i = 0; i < 64; ++i) {
          int k = kq * 64 + i;
          uint32_t pk = ahd[k * 128 + pcolI];
          float hv = hb[k];
          s0 += hv * __uint_as_float(pk << 16);
          s1 += hv * __uint_as_float(pk & 0xFFFF0000u);
        }
        scr[(kq * 32 + pl) * 2 + 0] = s0;
        scr[(kq * 32 + pl) * 2 + 1] = s1;
        __syncthreads();
        if (tid < 64) {
          float s = 0.f;
          #pragma unroll
          for (int k8 = 0; k8 < 8; ++k8) s += scr[(k8 * 32 + (tid >> 1)) * 2 + (tid & 1)];
          aw[tid] = s;
        }
        __syncthreads();
        {
          int w = tid >> 6, s32 = tid & 31, hi = (tid >> 5) & 1;
          for (int l = w * 2 + hi; l < 64; l += 8) {
            float sc = 0.f;
            #pragma unroll
            for (int q = 0; q < 2; ++q) {
              int al = s32 + (q << 5), ag = Q * 64 + al;
              sc += av2[ag] * tanh_f(wsp[WS_CT + (ab * 64 + l) * 256 + ag] + aw[al]);
            }
            sc = hsum32(sc);
            if (s32 == 0) araw[l] = sc;   // partial, no bias
          }
        }
        __syncthreads();
        if (tid < 16) bst4(wsp + WS_PSC + wg * 128 + tid * 4, *(vf4*)(araw + tid * 4));
      } else {
        // hist quarter: a in [Q*64, Q*64+64) -> 128 KB packed stream; also CACHE row t-1
        const uint32_t* hpd = (const uint32_t*)(wsp + WS_HHP);
        int al = tid & 63, kq = tid >> 6;
        float s1 = 0.f, s2 = 0.f;
        #pragma unroll 16
        for (int i = 0; i < 128; ++i) {
          int k = kq * 128 + i;
          uint32_t pk = hpd[k * 256 + Q * 64 + al];
          float hv = hb[k];
          s1 += hv * __uint_as_float(pk << 16);
          s2 += hv * __uint_as_float(pk & 0xFFFF0000u);
        }
        scr[kq * 64 + al] = s1;
        scr[256 + kq * 64 + al] = s2;
        __syncthreads();
        if (tid < 64) {
          float sa = 0.f, sb = 0.f;
          #pragma unroll
          for (int k4 = 0; k4 < 4; ++k4) { sa += scr[k4 * 64 + tid]; sb += scr[256 + k4 * 64 + tid]; }
          aw[tid] = sa;
          if (t > 0) wsp[WS_CACHE + (ab * 64 + (t - 1)) * 256 + Q * 64 + tid] = sb;  // same-WG quarter
        }
        __syncthreads();
        {
          int w = tid >> 6, s32 = tid & 31, hi = (tid >> 5) & 1;
          for (int l = w * 2 + hi; l < t; l += 8) {
            float sc = 0.f;
            #pragma unroll
            for (int q = 0; q < 2; ++q) {
              int al2 = s32 + (q << 5), ag = Q * 64 + al2;
              sc += av2[ag] * tanh_f(wsp[WS_CACHE + (ab * 64 + l) * 256 + ag] + abv[ag] + aw[al2]);
            }
            sc = hsum32(sc);
            if (s32 == 0) araw[l] = sc;
          }
          if (tid < 32) {  // z-score partial (unwritten hist rows = 0)
            float sc = 0.f;
            #pragma unroll
            for (int q = 0; q < 2; ++q) {
              int al2 = tid + (q << 5), ag = Q * 64 + al2;
              sc += av2[ag] * tanh_f(abv[ag] + aw[al2]);
            }
            sc = hsum32(sc);
            if (tid == 0) araw[64] = sc;
          }
        }
        __syncthreads();
        if (tid < 16) bst4(wsp + WS_PSC + wg * 128 + tid * 4, *(vf4*)(araw + tid * 4));
        if (tid == 16) bst(wsp + WS_PSC + wg * 128 + 64, araw[64]);
      }
      asm volatile("s_waitcnt vmcnt(0)" ::: "memory");
      __syncthreads();
      if (tid == 0)
        __hip_atomic_store(&flags[wg * 16 + 2], (unsigned)(t + 1), __ATOMIC_RELAXED, __HIP_MEMORY_SCOPE_SYSTEM);
    }

    // all WGs: gate-GEMM h part (zs holds h), par gather, par part
    gemm(1);
    __syncthreads();
    {
      #pragma unroll
      for (int j = 0; j < 8; ++j) {
        int i4 = tid + j * NT, b = i4 >> 7, k0 = (i4 << 2) & 511;
        int par = p.parent[b * 64 + t];
        vf4 v = {0.f, 0.f, 0.f, 0.f};
        if (t > 0 && par < t) v = *(const vf4*)(wsp + WS_HIST + (b * 64 + par) * 512 + k0);
        *(vf4*)(zs + b * 516 + k0) = v;
      }
    }
    __syncthreads();
    gemm(2);

    // att WGs: combine partials -> softmax -> einsum quarter
    if (isAtt) {
      if (tid < 4)
        while (__hip_atomic_load(&flags[(grp0 + tid) * 16 + 2], __ATOMIC_RELAXED, __HIP_MEMORY_SCOPE_SYSTEM) < (unsigned)(t + 1))
          __builtin_amdgcn_s_sleep(1);
      __syncthreads();
      const int NL = isHist ? 65 : 64;
      if (tid < NL) {
        const float* b0 = wsp + WS_PSC + grp0 * 128 + tid;
        vf4 s4 = bld4s(b0, b0 + 128, b0 + 256, b0 + 384);
        float s = ((s4.x + s4.y) + s4.z) + s4.w;   // fixed order: Q=0,1,2,3
        if (!isHist) araw[tid] = (p.cmask[ab * 64 + tid] > 0) ? -INFINITY : (s + ab2f);
        else         araw[tid] = s + hb2f;
      }
      __syncthreads();
      if (tid < 64) {
        if (!isHist) {
          float r = araw[tid];
          float mx = wmax(r), e = __expf(r - mx), sm = wsum(e);
          asmx[tid] = e / sm;
        } else {
          float r = (tid < t) ? araw[tid] : araw[64];
          float mx = wmax(r);                    // max over ALL t' (matches reference)
          float e = (tid < t) ? __expf(r - mx) : 0.f;
          float sm = wsum(e);
          asmx[tid] = e / (sm + 1e-7f);
        }
      }
      __syncthreads();
      {
        int dv = tid & 31, lq = tid >> 5;
        vf4 a0 = {0.f, 0.f, 0.f, 0.f};
        if (!isHist) {
          for (int l = lq; l < 64; l += 8) {
            float ca = asmx[l];
            vf4 cv = *(const vf4*)(p.ctx + (ab * 64 + l) * 512 + Q * 128 + dv * 4);
            a0.x += ca * cv.x; a0.y += ca * cv.y; a0.z += ca * cv.z; a0.w += ca * cv.w;
          }
        } else {
          for (int l = lq; l < t; l += 8) {
            float hv = asmx[l];
            vf4 cv = *(const vf4*)(wsp + WS_HIST + (ab * 64 + l) * 512 + Q * 128 + dv * 4);
            a0.x += hv * cv.x; a0.y += hv * cv.y; a0.z += hv * cv.z; a0.w += hv * cv.w;
          }
        }
        *(vf4*)(scr + tid * 4) = a0;
      }
      __syncthreads();
      if (tid < 32) {
        vf4 u = {0.f, 0.f, 0.f, 0.f};
        #pragma unroll
        for (int j = 0; j < 8; ++j) {
          vf4 v = *(vf4*)(scr + (j * 32 + tid) * 4);
          u.x += v.x; u.y += v.y; u.z += v.z; u.w += v.w;
        }
        if (!isHist) bst4(p.out + OUT_CTX + (ab * 64 + t) * 512 + Q * 128 + tid * 4, u);
        else         bst4(wsp + WS_HC + ab * 512 + Q * 128 + tid * 4, u);
      }
    }
    gsync();   // barrier Y: cv / hc published

    // ================= Phase B =================
    {
      #pragma unroll
      for (int j = 0; j < 8; ++j) {  // stage ctx_vec from out (cached; fresh address each step)
        int i4 = tid + j * NT, b = i4 >> 7, k0 = (i4 << 2) & 511;
        vf4 v = *(const vf4*)(p.out + OUT_CTX + (b * 64 + t) * 512 + k0);
        *(vf4*)(zs + b * 516 + k0) = v;
      }
    }
    __syncthreads();
    // issue HC bypass loads now; drain after gemm(3) so MALL latency hides
    vf4 rhc[8];
    {
      const float* q[8];
      #pragma unroll
      for (int j = 0; j < 8; ++j) { int i4 = tid + j * NT; q[j] = wsp + WS_HC + (i4 >> 7) * 512 + ((i4 << 2) & 511); }
      bld8_issue(rhc, q[0], q[1], q[2], q[3], q[4], q[5], q[6], q[7]);
    }
    gemm(3);
    __syncthreads();
    bwait8(rhc);
    #pragma unroll
    for (int j = 0; j < 8; ++j) { int i4 = tid + j * NT; *(vf4*)(zs + (i4 >> 7) * 516 + ((i4 << 2) & 511)) = rhc[j]; }
    __syncthreads();
    gemm(4);
    {
      float* s8 = scr + (kh * 16 + sub) * 8;
      #pragma unroll
      for (int i = 0; i < 4; ++i) { s8[i*2] = acc[i][0]; s8[i*2+1] = acc[i][1]; acc[i][0] = 0.f; acc[i][1] = 0.f; }
    }
    __syncthreads();
    if (t < 63) {
      #pragma unroll
      for (int j = 0; j < 8; ++j) {  // pre-stage X(t+1)
        int i4 = tid + j * NT, b = i4 >> 7, k0 = (i4 << 2) & 511;
        vf4 v = *(const vf4*)(p.X + (b * 64 + (t + 1)) * 512 + k0);
        *(vf4*)(zs + b * 516 + k0) = v;
      }
    }
    if (tid < 128) {
      int b = tid >> 3, c = tid & 7;  // c = quarter*2 + coloff
      int n = base + (c & 1) + 512 * (c >> 1);
      float g = p.bx[n];
      int sidx = (b >> 2) * 4 + (c >> 1);
      int aidx = (b & 3) * 2 + (c & 1);
      #pragma unroll
      for (int k2 = 0; k2 < 16; ++k2) g += scr[(k2 * 16 + sidx) * 8 + aidx];
      gld[b * 8 + c] = g;
    }
    __syncthreads();
    if (tid < 32) {
      int b = tid >> 1, dj = tid & 1;
      int d = base + dj;
      float gi = gld[b*8 + 0 + dj];
      float gf = gld[b*8 + 2 + dj];
      float gg = gld[b*8 + 4 + dj];
      float go = gld[b*8 + 6 + dj];
      float i_ = sigm_f(gi), f_ = sigm_f(gf), o_ = sigm_f(go);
      float cn = f_ * cprev + i_ * tanh_f(gg);
      float hn = o_ * tanh_f(cn);
      float m_ = p.mask[b * 64 + t];
      hn = (1.f - m_) * hprev + m_ * hn;
      cn = (1.f - m_) * cprev + m_ * cn;
      hprev = hn; cprev = cn;
      bst(wsp + WS_HIST + (b * 64 + t) * 512 + d, hn);
      p.out[OUT_HS + (b * 64 + t) * 512 + d] = hn;
      p.out[OUT_CS + (b * 64 + t) * 512 + d] = cn;
    }
    if (t < 63) {
      gemm(0);   // x-part for t+1 (zs holds X(t+1))
      gsync();   // barrier X: h(t) published
    }
  }
}

extern "C" void kernel_launch(void* const* d_in, const int* in_sizes, int n_in,
                              void* d_out, int out_size, void* d_ws, size_t ws_size,
                              hipStream_t stream) {
  CAParams p;
  p.X      = (const float*)d_in[0];
  p.ctx    = (const float*)d_in[1];
  p.parent = (const int*)  d_in[2];
  p.cmask  = (const int*)  d_in[3];
  p.mask   = (const float*)d_in[4];
  p.Wx = (const float*)d_in[5];  p.bx = (const float*)d_in[6];
  p.U  = (const float*)d_in[7];  p.C  = (const float*)d_in[8];
  p.P  = (const float*)d_in[9];  p.H  = (const float*)d_in[10];
  p.acW1 = (const float*)d_in[11]; p.ab1 = (const float*)d_in[12];
  p.ahW1 = (const float*)d_in[13]; p.aW2 = (const float*)d_in[14]; p.ab2 = (const float*)d_in[15];
  p.hhW  = (const float*)d_in[16]; p.hhb = (const float*)d_in[17];
  p.hthW1= (const float*)d_in[18]; p.hW2 = (const float*)d_in[19]; p.hb2 = (const float*)d_in[20];
  p.out = (float*)d_out;
  p.ws  = (float*)d_ws;

  // reset barrier + att flags (restart each launch)
  (void)hipMemsetAsync(d_ws, 0, 16384, stream);

  static_assert(LDS_FLOATS * 4 <= 160 * 1024, "LDS budget");
  (void)hipFuncSetAttribute((const void*)condatt_kernel,
                      hipFuncAttributeMaxDynamicSharedMemorySize, LDS_FLOATS * 4);
  hipLaunchKernelGGL(condatt_kernel, dim3(NWG), dim3(NT), LDS_FLOATS * 4, stream, p);
}